// Round 10
// baseline (385.446 us; speedup 1.0000x reference)
//
#include <hip/hip_runtime.h>
#include <math.h>

// downprompt: fused elementwise + 7-way cosine-sim + softmax.
// v11: single-stream bursts per wave (DRAM page locality probe).
// Evidence: dual-stream nt reads cap at ~4.0 TB/s; single-stream fill
// writes 6.7 TB/s; copy (two interleaved streams) = 3.15/direction.
// Split algebraically: r = e + u, e = elu1(coef*s), u = 0.1*t:
//   acc[c] = sum(e*av) + sum(u*av);  acc7 = sum(e^2) + sum(u*(2e+u))
// Pass 1 reads ONLY seq (8KB contiguous burst per wave), keeps e in 32
// registers; sched_barrier(0); pass 2 reads ONLY seq1, folds in t-terms.
// Geometry (from v10): 8 lanes/row x 8 rows/wave, every global read =
// aligned 128B line, nt loads/stores, coef+ave LDS broadcast.

typedef float f32x4 __attribute__((ext_vector_type(4)));

__device__ __forceinline__ float elu1(float x) {
    return x > 0.0f ? x : __expf(x) - 1.0f;
}

__device__ __forceinline__ float wave_sum(float v) {
#pragma unroll
    for (int off = 32; off > 0; off >>= 1)
        v += __shfl_xor(v, off, 64);
    return v;
}

__global__ __launch_bounds__(256) void downprompt_kernel(
    const float* __restrict__ seq,
    const float* __restrict__ seq1,
    const float* __restrict__ prompt,
    const float* __restrict__ w_np,
    const float* __restrict__ w_ds,
    const float* __restrict__ w_df,
    const float* __restrict__ ave,
    float* __restrict__ out,
    int N)
{
    __shared__ float s_coef[256];
    __shared__ float s_ave[7][256];

    const int tid  = threadIdx.x;
    const int lane = tid & 63;

    // ---- block setup: stage coef[d] and ave into LDS ----
    {
        const float a  = w_df[0];
        const float b  = w_df[1];
        const float w0 = w_np[0], w1 = w_np[1], w2 = w_np[2];
        const float pr = w0 * prompt[tid] + w1 * prompt[256 + tid]
                       + w2 * prompt[512 + tid];
        s_coef[tid] = a * (1.0f + elu1(pr)) + b * w_ds[tid];
#pragma unroll
        for (int c = 0; c < 7; ++c)
            s_ave[c][tid] = ave[c * 256 + tid];
    }
    __syncthreads();

    // ---- per-wave: prototype norms (once per wave) ----
    float na[7];
#pragma unroll
    for (int c = 0; c < 7; ++c) {
        const float4 v = *(const float4*)&s_ave[c][lane << 2];
        na[c] = sqrtf(wave_sum(v.x * v.x + v.y * v.y + v.z * v.z + v.w * v.w));
    }

    // ---- 8 lanes per row, 8 rows per wave ----
    const int ph  = lane & 7;    // 16B phase within a 128B line (0..7)
    const int ph4 = ph << 2;     // float offset of this lane's 16B
    const int sub = lane >> 3;   // row within group (0..7)
    const int wavesPerBlock = blockDim.x >> 6;
    const int gwave = blockIdx.x * wavesPerBlock + (tid >> 6);
    const int nwave = gridDim.x * wavesPerBlock;
    const int ngroups = (N + 7) >> 3;

    for (int g = gwave; g < ngroups; g += nwave) {
        const int row = (g << 3) + sub;
        if (row >= N) continue;   // group-uniform: shuffles stay safe

        const float* ps = seq  + (size_t)row * 256 + ph4;
        const float* pt = seq1 + (size_t)row * 256 + ph4;

        float acc[8];
#pragma unroll
        for (int k = 0; k < 8; ++k) acc[k] = 0.0f;

        float ev[8][4];   // elu values, static indices only -> registers

        // ---- pass 1: seq ONLY (single-stream 8KB burst per wave) ----
#pragma unroll
        for (int i = 0; i < 8; ++i) {
            const int col = (i << 5) + ph4;
            const f32x4 s = __builtin_nontemporal_load(
                                (const f32x4*)(ps + (i << 5)));
            const float4 cf = *(const float4*)&s_coef[col];

            const float e0 = elu1(cf.x * s[0]);
            const float e1 = elu1(cf.y * s[1]);
            const float e2 = elu1(cf.z * s[2]);
            const float e3 = elu1(cf.w * s[3]);
            ev[i][0] = e0; ev[i][1] = e1; ev[i][2] = e2; ev[i][3] = e3;

            acc[7] += e0 * e0 + e1 * e1 + e2 * e2 + e3 * e3;
#pragma unroll
            for (int c = 0; c < 7; ++c) {
                const float4 av = *(const float4*)&s_ave[c][col];
                acc[c] += e0 * av.x + e1 * av.y + e2 * av.z + e3 * av.w;
            }
        }

        __builtin_amdgcn_sched_barrier(0);  // keep the two streams separate

        // ---- pass 2: seq1 ONLY (single-stream 8KB burst per wave) ----
#pragma unroll
        for (int i = 0; i < 8; ++i) {
            const int col = (i << 5) + ph4;
            const f32x4 t = __builtin_nontemporal_load(
                                (const f32x4*)(pt + (i << 5)));
            const float u0 = 0.1f * t[0];
            const float u1 = 0.1f * t[1];
            const float u2 = 0.1f * t[2];
            const float u3 = 0.1f * t[3];

            // r^2 = e^2 + u*(2e+u); e^2 done in pass 1
            acc[7] += u0 * (2.0f * ev[i][0] + u0)
                    + u1 * (2.0f * ev[i][1] + u1)
                    + u2 * (2.0f * ev[i][2] + u2)
                    + u3 * (2.0f * ev[i][3] + u3);
#pragma unroll
            for (int c = 0; c < 7; ++c) {
                const float4 av = *(const float4*)&s_ave[c][col];
                acc[c] += u0 * av.x + u1 * av.y + u2 * av.z + u3 * av.w;
            }
        }

        // reduce the 8 partials across the 8 lanes of this row's group
#pragma unroll
        for (int off = 1; off <= 4; off <<= 1) {
#pragma unroll
            for (int k = 0; k < 8; ++k)
                acc[k] += __shfl_xor(acc[k], off, 64);
        }

        // softmax over cosine sims (redundant x8 within the group)
        const float nr = sqrtf(acc[7]);
        float sims[7];
        float m = -INFINITY;
#pragma unroll
        for (int c = 0; c < 7; ++c) {
            const float den = fmaxf(nr * na[c], 1e-8f);
            sims[c] = acc[c] * __builtin_amdgcn_rcpf(den);
            m = fmaxf(m, sims[c]);
        }
        float e[7], sum = 0.0f;
#pragma unroll
        for (int c = 0; c < 7; ++c) {
            e[c] = __expf(sims[c] - m);
            sum += e[c];
        }
        const float inv = __builtin_amdgcn_rcpf(sum);

        // lane ph (<7) writes exactly class c=ph (static per-lane select)
        float mye = e[0];
#pragma unroll
        for (int c = 1; c < 7; ++c)
            if (ph == c) mye = e[c];

        if (ph < 7)
            __builtin_nontemporal_store(mye * inv, out + (size_t)row * 7 + ph);
    }
}

extern "C" void kernel_launch(void* const* d_in, const int* in_sizes, int n_in,
                              void* d_out, int out_size, void* d_ws, size_t ws_size,
                              hipStream_t stream) {
    const float* seq    = (const float*)d_in[0];
    const float* seq1   = (const float*)d_in[1];
    const float* prompt = (const float*)d_in[2];
    const float* w_np   = (const float*)d_in[3];
    const float* w_ds   = (const float*)d_in[4];
    const float* w_df   = (const float*)d_in[5];
    const float* ave    = (const float*)d_in[6];
    float* out = (float*)d_out;

    const int N = in_sizes[0] / 256;          // 200000
    const int ngroups = (N + 7) / 8;          // 25000 row-groups of 8
    const int wavesPerBlock = 4;
    // one 8-row group per wave: 6250 blocks = 25000 waves
    int blocks = (ngroups + wavesPerBlock - 1) / wavesPerBlock;
    if (blocks < 1) blocks = 1;

    downprompt_kernel<<<blocks, 256, 0, stream>>>(seq, seq1, prompt, w_np, w_ds,
                                                  w_df, ave, out, N);
}